// Round 5
// baseline (64.200 us; speedup 1.0000x reference)
//
#include <hip/hip_runtime.h>
#include <stdint.h>

#define M_TOTAL 16384
#define N_TOTAL 1024
#define K_TOTAL 1024

using f32x4  = __attribute__((ext_vector_type(4))) float;
using bf16x8 = __attribute__((ext_vector_type(8))) short;
using bf16x4 = __attribute__((ext_vector_type(4))) short;

__device__ __forceinline__ unsigned packrne(float x, float y) {
    unsigned ux = __builtin_bit_cast(unsigned, x);
    unsigned uy = __builtin_bit_cast(unsigned, y);
    ux += 0x7fffu + ((ux >> 16) & 1u);
    uy += 0x7fffu + ((uy >> 16) & 1u);
    return (ux >> 16) | (uy & 0xffff0000u);
}

// ---------------- kernel 1: cvt X -> bf16 rowmajor, W -> bf16 FRAG-ORDER ----
// Wf layout: 16B chunk index (J, h, l): J = 16-col group (64), h = 32-k half
// (32), l = lane (64) with cl=l&15, kb=l>>4. Content = W[J*16+cl][h*32+kb*8 ..+8].
// A GEMM wave then loads its B-fragment as ONE contiguous 1KB dwordx4 load.
#define N8X (M_TOTAL * K_TOTAL / 8)   // 2097152 (X 16B-chunks)
#define NWF (N_TOTAL * K_TOTAL / 8)   // 131072  (Wf 16B-chunks)
__global__ __launch_bounds__(256) void cvt2_kernel(
    const float* __restrict__ X, const float* __restrict__ W,
    uint4* __restrict__ Xb, uint4* __restrict__ Wf)
{
    const int i = blockIdx.x * 256 + threadIdx.x;
    if (i < N8X) {
        const f32x4* p = (const f32x4*)X + (size_t)i * 2;
        const f32x4 a = p[0], b = p[1];
        uint4 r;
        r.x = packrne(a[0], a[1]);
        r.y = packrne(a[2], a[3]);
        r.z = packrne(b[0], b[1]);
        r.w = packrne(b[2], b[3]);
        Xb[i] = r;
    } else {
        const int idx = i - N8X;          // [0, NWF)
        const int J  = idx >> 11;         // 2048 chunks per J-group (32KB)
        const int rem = idx & 2047;
        const int h  = rem >> 6;
        const int l  = rem & 63;
        const int cl = l & 15, kb = l >> 4;
        const float* src = W + (size_t)(J * 16 + cl) * K_TOTAL + h * 32 + kb * 8;
        const f32x4 a = *(const f32x4*)src;
        const f32x4 b = *(const f32x4*)(src + 4);
        uint4 r;
        r.x = packrne(a[0], a[1]);
        r.y = packrne(a[2], a[3]);
        r.z = packrne(b[0], b[1]);
        r.w = packrne(b[2], b[3]);
        Wf[idx] = r;
    }
}

// ---------------- kernel 2: 256x256 GEMM, A via LDS, B direct-to-reg --------
// C[m][n] = sum_k Xb[m][k]*Wf-frag + bias[n].
// 8 waves (2M x 4N), wave-tile 128x64. LDS = A only, 2 x 32KB double buffer.
// Per tile: vmcnt(8) -> barrier -> issue B(t+1) -> 2 phases {8 ds_read aF +
// 32 MFMA setprio-wrapped} -> barrier -> stage A(t+2).
#define BM 256
#define BN 256
#define BK 64
#define NTILES (K_TOTAL / BK)       // 16
#define NBM (M_TOTAL / BM)          // 64
#define NBN (N_TOTAL / BN)          // 4
#define NWG (NBM * NBN)             // 256

__global__ __launch_bounds__(512, 2) void gemm8_kernel(
    const unsigned short* __restrict__ Xb, const unsigned short* __restrict__ Wfu,
    const float* __restrict__ bias, float* __restrict__ C)
{
    __shared__ short smem[2 * 16384];   // 64 KB: A0 @0, A1 @32768 bytes

    const int tid  = threadIdx.x;
    const int lane = tid & 63;
    const int wave = tid >> 6;      // 0..7
    const int wr = wave >> 2;       // 0..1 : 128-row strip
    const int wc = wave & 3;        // 0..3 : 64-col strip

    // XCD-chunked swizzle (verified r2-r4: X panel fetched ~once)
    const int bid  = blockIdx.x;
    const int work = (bid & 7) * (NWG / 8) + (bid >> 3);
    const int bm = work >> 2;
    const int bn = work & 3;
    const int m0 = bm * BM, n0 = bn * BN;

    // A staging (round-4 proven): linear gload_lds dest + pre-swizzled source;
    // LDS slot s of row r holds k-group s ^ (r&7) -> swizzled ds_read is
    // conflict-free.
    const int srow64 = wave * 8 + (lane >> 3);
    const int kge    = ((lane & 7) ^ ((lane >> 3) & 7)) * 8;

    auto stage_A = [&](int t, int buf) {
        const int k0 = t * BK;
        #pragma unroll
        for (int j = 0; j < 4; ++j) {
            __builtin_amdgcn_global_load_lds(
                (const __attribute__((address_space(1))) void*)
                    (Xb + (size_t)(m0 + j * 64 + srow64) * K_TOTAL + k0 + kge),
                (__attribute__((address_space(3))) void*)
                    ((char*)smem + buf * 32768 + j * 8192 + wave * 1024),
                16, 0, 0);
        }
    };

    // B direct loads: frag (jj, hh) of tile t at Wf chunk
    // (Jbase+jj)*2048 + (t*2+hh)*64 + lane  (16B units) -- 1KB/wave contiguous.
    const uint4* Wf = (const uint4*)Wfu;
    const int Jbase = (n0 + wc * 64) >> 4;

    auto load_B = [&](int t, bf16x8 (&B)[4][2]) {
        #pragma unroll
        for (int jj = 0; jj < 4; ++jj)
            #pragma unroll
            for (int hh = 0; hh < 2; ++hh)
                B[jj][hh] = __builtin_bit_cast(bf16x8,
                    Wf[(size_t)(Jbase + jj) * 2048 + (t * 2 + hh) * 64 + lane]);
    };

    const int cl = lane & 15;
    const int kb = lane >> 4;

    f32x4 acc[8][4] = {};

    auto iter_body = [&](int t, bf16x8 (&Bcur)[4][2], bf16x8 (&Bnxt)[4][2]) {
        const int buf = t & 1;
        // A(t) landed for ALL waves' chunks; A(t+1) (newest 8) keeps flying.
        asm volatile("s_waitcnt vmcnt(8)" ::: "memory");
        __builtin_amdgcn_sched_barrier(0);
        __builtin_amdgcn_s_barrier();
        __builtin_amdgcn_sched_barrier(0);

        if (t + 1 < NTILES) load_B(t + 1, Bnxt);   // issue-early; used next iter

        const char* Abase = (const char*)smem + buf * 32768;
        bf16x8 aF[4][2];
        // ---- phase 0: rows 0-63 of wave strip ----
        #pragma unroll
        for (int i = 0; i < 4; ++i) {
            const int ar = wr * 128 + i * 16 + cl;
            const int rs = ar & 7;
            aF[i][0] = *(const bf16x8*)(Abase + ar * 128 + ((kb       ^ rs) << 4));
            aF[i][1] = *(const bf16x8*)(Abase + ar * 128 + (((kb + 4) ^ rs) << 4));
        }
        __builtin_amdgcn_s_setprio(1);
        #pragma unroll
        for (int i = 0; i < 4; ++i)
            #pragma unroll
            for (int jj = 0; jj < 4; ++jj) {
                acc[i][jj] = __builtin_amdgcn_mfma_f32_16x16x32_bf16(aF[i][0], Bcur[jj][0], acc[i][jj], 0, 0, 0);
                acc[i][jj] = __builtin_amdgcn_mfma_f32_16x16x32_bf16(aF[i][1], Bcur[jj][1], acc[i][jj], 0, 0, 0);
            }
        __builtin_amdgcn_s_setprio(0);
        // ---- phase 1: rows 64-127 ----
        #pragma unroll
        for (int i = 0; i < 4; ++i) {
            const int ar = wr * 128 + 64 + i * 16 + cl;
            const int rs = ar & 7;
            aF[i][0] = *(const bf16x8*)(Abase + ar * 128 + ((kb       ^ rs) << 4));
            aF[i][1] = *(const bf16x8*)(Abase + ar * 128 + (((kb + 4) ^ rs) << 4));
        }
        __builtin_amdgcn_s_setprio(1);
        #pragma unroll
        for (int i = 0; i < 4; ++i)
            #pragma unroll
            for (int jj = 0; jj < 4; ++jj) {
                acc[4 + i][jj] = __builtin_amdgcn_mfma_f32_16x16x32_bf16(aF[i][0], Bcur[jj][0], acc[4 + i][jj], 0, 0, 0);
                acc[4 + i][jj] = __builtin_amdgcn_mfma_f32_16x16x32_bf16(aF[i][1], Bcur[jj][1], acc[4 + i][jj], 0, 0, 0);
            }
        __builtin_amdgcn_s_setprio(0);

        // all waves done reading buf before restage overwrites it
        __builtin_amdgcn_sched_barrier(0);
        __builtin_amdgcn_s_barrier();
        __builtin_amdgcn_sched_barrier(0);
        if (t + 2 < NTILES) stage_A(t + 2, buf);
    };

    // ---- pipeline ----
    bf16x8 B0r[4][2], B1r[4][2];
    load_B(0, B0r);          // oldest VMEM -> forced by first vmcnt(8)
    stage_A(0, 0);
    stage_A(1, 1);
    #pragma unroll 1
    for (int t = 0; t < NTILES; t += 2) {
        iter_body(t,     B0r, B1r);
        iter_body(t + 1, B1r, B0r);
    }

    // ---- epilogue: D element (row=(lane>>4)*4+r, col=lane&15) [m89] ----
    const int r0 = (lane >> 4) * 4;
    #pragma unroll
    for (int ni = 0; ni < 4; ++ni) {
        const int n = n0 + wc * 64 + ni * 16 + cl;
        const float bvv = bias[n];
        #pragma unroll
        for (int mi = 0; mi < 8; ++mi) {
            const int m = m0 + wr * 128 + mi * 16 + r0;
            #pragma unroll
            for (int r = 0; r < 4; ++r)
                C[(size_t)(m + r) * N_TOTAL + n] = acc[mi][ni][r] + bvv;
        }
    }
}

// ---------------- fallback: round-1 single kernel (known-good) --------------
__device__ __forceinline__ short f2bf(float f) {
    unsigned u = __builtin_bit_cast(unsigned, f);
    u += 0x7fffu + ((u >> 16) & 1u);
    return (short)(u >> 16);
}

#define FBM 128
#define FBN 128
#define FNWG ((M_TOTAL / FBM) * (N_TOTAL / FBN))   // 1024

__global__ __launch_bounds__(256) void fb_gemm_bias_kernel(
    const float* __restrict__ X, const float* __restrict__ W,
    const float* __restrict__ bias, float* __restrict__ C)
{
    __shared__ short As[FBM * BK];
    __shared__ short Bs[FBN * BK];

    const int tid  = threadIdx.x;
    const int lane = tid & 63;
    const int wave = tid >> 6;
    const int wr = wave >> 1;
    const int wc = wave & 1;

    const int bid  = blockIdx.x;
    const int work = (bid & 7) * (FNWG / 8) + (bid >> 3);
    const int bm = work >> 3;
    const int bn = work & 7;
    const int m0 = bm * FBM, n0 = bn * FBN;

    const int srow  = tid >> 4;
    const int scol4 = tid & 15;

    f32x4 acc[4][4] = {};
    char* const Ab = (char*)As;
    char* const Bb = (char*)Bs;

    for (int k0 = 0; k0 < K_TOTAL; k0 += BK) {
        __syncthreads();
        #pragma unroll
        for (int pass = 0; pass < 8; ++pass) {
            const int row = srow + pass * 16;
            const int off = (row * (BK * 2) + scol4 * 8) ^ ((row & 7) << 4);
            {
                const f32x4 v = *(const f32x4*)(X + (size_t)(m0 + row) * K_TOTAL + k0 + scol4 * 4);
                bf16x4 b;
                b[0] = f2bf(v[0]); b[1] = f2bf(v[1]); b[2] = f2bf(v[2]); b[3] = f2bf(v[3]);
                *(bf16x4*)(Ab + off) = b;
            }
            {
                const f32x4 v = *(const f32x4*)(W + (size_t)(n0 + row) * K_TOTAL + k0 + scol4 * 4);
                bf16x4 b;
                b[0] = f2bf(v[0]); b[1] = f2bf(v[1]); b[2] = f2bf(v[2]); b[3] = f2bf(v[3]);
                *(bf16x4*)(Bb + off) = b;
            }
        }
        __syncthreads();

        #pragma unroll
        for (int ks = 0; ks < 2; ++ks) {
            const int kel = ks * 32 + ((lane >> 4) << 3);
            bf16x8 af[4], bfr[4];
            #pragma unroll
            for (int i = 0; i < 4; ++i) {
                const int arow = wr * 64 + i * 16 + (lane & 15);
                af[i]  = *(const bf16x8*)(Ab + ((arow * (BK * 2) + kel * 2) ^ ((arow & 7) << 4)));
                const int brow = wc * 64 + i * 16 + (lane & 15);
                bfr[i] = *(const bf16x8*)(Bb + ((brow * (BK * 2) + kel * 2) ^ ((brow & 7) << 4)));
            }
            #pragma unroll
            for (int mi = 0; mi < 4; ++mi)
                #pragma unroll
                for (int ni = 0; ni < 4; ++ni)
                    acc[mi][ni] = __builtin_amdgcn_mfma_f32_16x16x32_bf16(
                        af[mi], bfr[ni], acc[mi][ni], 0, 0, 0);
        }
    }

    const int cl = lane & 15;
    const int r0 = (lane >> 4) * 4;
    #pragma unroll
    for (int ni = 0; ni < 4; ++ni) {
        const int n = n0 + wc * 64 + ni * 16 + cl;
        const float bvv = bias[n];
        #pragma unroll
        for (int mi = 0; mi < 4; ++mi) {
            const int m = m0 + wr * 64 + mi * 16 + r0;
            #pragma unroll
            for (int r = 0; r < 4; ++r)
                C[(size_t)(m + r) * N_TOTAL + n] = acc[mi][ni][r] + bvv;
        }
    }
}

extern "C" void kernel_launch(void* const* d_in, const int* in_sizes, int n_in,
                              void* d_out, int out_size, void* d_ws, size_t ws_size,
                              hipStream_t stream) {
    // inputs: 0:X 1:Wq 2:bq 3:Wk 4:bk 5:Wv 6:bv
    // softmax rows sum to 1 => out = X @ Wv^T + bv exactly.
    const float* X  = (const float*)d_in[0];
    const float* Wv = (const float*)d_in[5];
    const float* bv = (const float*)d_in[6];
    float* out = (float*)d_out;

    const size_t XB_BYTES = (size_t)M_TOTAL * K_TOTAL * 2;   // 32 MiB
    const size_t WF_BYTES = (size_t)N_TOTAL * K_TOTAL * 2;   // 2 MiB

    if (ws_size >= XB_BYTES + WF_BYTES) {
        unsigned short* Xb = (unsigned short*)d_ws;
        unsigned short* Wf = (unsigned short*)((char*)d_ws + XB_BYTES);
        cvt2_kernel<<<dim3((N8X + NWF) / 256), dim3(256), 0, stream>>>(
            X, Wv, (uint4*)Xb, (uint4*)Wf);
        gemm8_kernel<<<dim3(NWG), dim3(512), 0, stream>>>(Xb, Wf, bv, out);
    } else {
        fb_gemm_bias_kernel<<<dim3(FNWG), dim3(256), 0, stream>>>(X, Wv, bv, out);
    }
}

// Round 6
// 60.605 us; speedup vs baseline: 1.0593x; 1.0593x over previous
//
#include <hip/hip_runtime.h>
#include <stdint.h>

#define M_TOTAL 16384
#define N_TOTAL 1024
#define K_TOTAL 1024

using f32x4  = __attribute__((ext_vector_type(4))) float;
using bf16x8 = __attribute__((ext_vector_type(8))) short;
using bf16x4 = __attribute__((ext_vector_type(4))) short;

#define AS1 __attribute__((address_space(1)))
#define AS3 __attribute__((address_space(3)))
#define SB() __builtin_amdgcn_sched_barrier(0)

__device__ __forceinline__ unsigned packrne(float x, float y) {
    unsigned ux = __builtin_bit_cast(unsigned, x);
    unsigned uy = __builtin_bit_cast(unsigned, y);
    ux += 0x7fffu + ((ux >> 16) & 1u);
    uy += 0x7fffu + ((uy >> 16) & 1u);
    return (ux >> 16) | (uy & 0xffff0000u);
}

// ---------------- kernel 1: fused fp32->bf16 convert (X and Wv, row-major) --
#define N8X (M_TOTAL * K_TOTAL / 8)   // 2097152
#define N8W (N_TOTAL * K_TOTAL / 8)   // 131072
__global__ __launch_bounds__(256) void cvt2_kernel(
    const float* __restrict__ X, const float* __restrict__ W,
    uint4* __restrict__ Xb, uint4* __restrict__ Wb)
{
    const int i = blockIdx.x * 256 + threadIdx.x;
    const float* src; uint4* dst; int idx;
    if (i < N8X) { src = X; dst = Xb; idx = i; }
    else         { src = W; dst = Wb; idx = i - N8X; }
    const f32x4* p = (const f32x4*)src + (size_t)idx * 2;
    const f32x4 a = p[0], b = p[1];
    uint4 r;
    r.x = packrne(a[0], a[1]);
    r.y = packrne(a[2], a[3]);
    r.z = packrne(b[0], b[1]);
    r.w = packrne(b[2], b[3]);
    dst[idx] = r;
}

// ---------------- kernel 2: 256x256 8-phase counted-vmcnt bf16 GEMM ---------
// m201 template port. 8 waves (2M x 4N), wave-tile 128x64, BK=64, dbuf=2.
// LDS 128KB. Per K-tile: 4 phases, each {ds_read subtile + stage ONE
// half-tile -> barrier -> lgkmcnt(0) -> setprio'd 16 MFMA -> counted vmcnt
// -> barrier}. vmcnt(4) at P1/P2/P4 (never 0 in main loop).
//
// Half-tile packing (consumption-order): A packed row q: q = ha*128 + wr*64
// + off64  for actual row r = wr*128 + ha*64 + off64 (each wave's lower-64
// rows form half 0). B packed row p: p = hb*128 + wc*32 + off32 for col
// c = wc*64 + hb*32 + off32. XOR-swizzle: 16B slot g of packed row u holds
// k-group g ^ (u&7)  (realized by pre-swizzled global source, linear
// gload_lds dest; ds_read applies the same XOR).
#define BM 256
#define BN 256
#define BK 64
#define NTILES (K_TOTAL / BK)       // 16
#define NBM (M_TOTAL / BM)          // 64
#define NBN (N_TOTAL / BN)          // 4
#define NWG (NBM * NBN)             // 256

__global__ __launch_bounds__(512) void gemm8p_kernel(
    const unsigned short* __restrict__ Xb, const unsigned short* __restrict__ Wb,
    const float* __restrict__ bias, float* __restrict__ C)
{
    __shared__ __align__(16) char smem[131072];   // A: [0,64K) 2 dbuf; B: [64K,128K)

    const int tid  = threadIdx.x;
    const int lane = tid & 63;
    const int wave = tid >> 6;      // 0..7
    const int wr = wave >> 2;       // 0..1 : 128-row strip
    const int wc = wave & 3;        // 0..3 : 64-col strip

    // XCD-chunked swizzle (verified r2-r5: X panel fetched ~once)
    const int bid  = blockIdx.x;
    const int work = (bid & 7) * (NWG / 8) + (bid >> 3);
    const int bm = work >> 2;
    const int bn = work & 3;
    const int m0 = bm * BM, n0 = bn * BN;

    // staging: per stage-op lane l covers packed row base+(l>>3), slot l&7,
    // source k-group (l&7)^((l>>3)&7)  [linear dest + pre-swizzled source]
    const int kge = (((lane & 7) ^ ((lane >> 3) & 7)) << 3);

    auto stage_A = [&](int tt, int b, int ha) {
        #pragma unroll
        for (int j = 0; j < 2; ++j) {
            const int qb  = ha * 128 + wave * 16 + j * 8;
            const int row = ((qb >> 6) & 1) * 128 + ha * 64 + (qb & 63) + (lane >> 3);
            __builtin_amdgcn_global_load_lds(
                (const AS1 void*)(Xb + (size_t)(m0 + row) * K_TOTAL + tt * BK + kge),
                (AS3 void*)(smem + b * 32768 + qb * 128), 16, 0, 0);
        }
    };
    auto stage_B = [&](int tt, int b, int hb) {
        #pragma unroll
        for (int j = 0; j < 2; ++j) {
            const int pb  = hb * 128 + wave * 16 + j * 8;
            const int col = ((pb >> 5) & 3) * 64 + hb * 32 + (pb & 31) + (lane >> 3);
            __builtin_amdgcn_global_load_lds(
                (const AS1 void*)(Wb + (size_t)(n0 + col) * K_TOTAL + tt * BK + kge),
                (AS3 void*)(smem + 65536 + b * 32768 + pb * 128), 16, 0, 0);
        }
    };

    const int cl = lane & 15;
    const int kb = lane >> 4;          // 0..3
    const int sw = cl & 7;             // swizzle term for frag reads

    bf16x8 aF[4][2], bLo[2][2], bHi[2][2];
    f32x4 acc[8][4] = {};

    auto read_A = [&](int b, int ha) {
        const char* Ab = smem + b * 32768;
        #pragma unroll
        for (int i = 0; i < 4; ++i) {
            const int q = ha * 128 + wr * 64 + i * 16 + cl;
            aF[i][0] = *(const bf16x8*)(Ab + q * 128 + ((kb       ^ sw) << 4));
            aF[i][1] = *(const bf16x8*)(Ab + q * 128 + (((kb + 4) ^ sw) << 4));
        }
    };
    auto read_B = [&](int b, int hb, bf16x8 (&B)[2][2]) {
        const char* Bb = smem + 65536 + b * 32768;
        #pragma unroll
        for (int j = 0; j < 2; ++j) {
            const int p = hb * 128 + wc * 32 + j * 16 + cl;
            B[j][0] = *(const bf16x8*)(Bb + p * 128 + ((kb       ^ sw) << 4));
            B[j][1] = *(const bf16x8*)(Bb + p * 128 + (((kb + 4) ^ sw) << 4));
        }
    };

#define MFMA_Q(MI0, NI0, BREG)                                                      \
    __builtin_amdgcn_s_setprio(1);                                                  \
    _Pragma("unroll")                                                               \
    for (int i = 0; i < 4; ++i) {                                                   \
        _Pragma("unroll")                                                           \
        for (int j = 0; j < 2; ++j) {                                               \
            acc[(MI0) + i][(NI0) + j] = __builtin_amdgcn_mfma_f32_16x16x32_bf16(    \
                aF[i][0], BREG[j][0], acc[(MI0) + i][(NI0) + j], 0, 0, 0);          \
            acc[(MI0) + i][(NI0) + j] = __builtin_amdgcn_mfma_f32_16x16x32_bf16(    \
                aF[i][1], BREG[j][1], acc[(MI0) + i][(NI0) + j], 0, 0, 0);          \
        }                                                                           \
    }                                                                               \
    __builtin_amdgcn_s_setprio(0);

#define BARRIER() SB(); __builtin_amdgcn_s_barrier(); SB()
#define LGKM0()   asm volatile("s_waitcnt lgkmcnt(0)" ::: "memory"); SB()
#define VM(N)     asm volatile("s_waitcnt vmcnt(" #N ")" ::: "memory"); SB()

    // ---- prologue: tile 0 halves in consumption order ----
    stage_A(0, 0, 0);    // A-h0(0)
    stage_B(0, 0, 0);    // B-h0(0)
    stage_B(0, 0, 1);    // B-h1(0)
    stage_A(0, 0, 1);    // A-h1(0)
    VM(4);               // A-h0(0), B-h0(0) landed
    BARRIER();

    #pragma unroll 1
    for (int t = 0; t < NTILES; ++t) {
        const int buf = t & 1, nbuf = buf ^ 1;
        const bool nx = (t + 1 < NTILES);

        // ---- P1: read A-h0(t)+B-h0(t); stage A-h0(t+1); MFMA Q(lo,lo) ----
        read_A(buf, 0);
        read_B(buf, 0, bLo);
        if (nx) stage_A(t + 1, nbuf, 0);
        BARRIER();
        LGKM0();
        MFMA_Q(0, 0, bLo);
        if (nx) { VM(4); } else { VM(2); }   // force B-h1(t)
        BARRIER();

        // ---- P2: read B-h1(t); stage B-h0(t+1); MFMA Q(lo,hi) ----
        read_B(buf, 1, bHi);
        if (nx) stage_B(t + 1, nbuf, 0);
        BARRIER();
        LGKM0();
        MFMA_Q(0, 2, bHi);
        if (nx) { VM(4); } else { VM(0); }   // force A-h1(t)
        BARRIER();

        // ---- P3: read A-h1(t); stage B-h1(t+1); MFMA Q(hi,hi) ----
        read_A(buf, 1);
        if (nx) stage_B(t + 1, nbuf, 1);
        BARRIER();
        LGKM0();
        MFMA_Q(4, 2, bHi);
        BARRIER();

        // ---- P4: (frags in regs); stage A-h1(t+1); MFMA Q(hi,lo) ----
        if (nx) stage_A(t + 1, nbuf, 1);
        BARRIER();
        MFMA_Q(4, 0, bLo);
        if (nx) { VM(4); }                   // force A-h0(t+1), B-h0(t+1)
        BARRIER();
    }

    // ---- epilogue: D element (row=(lane>>4)*4+r, col=lane&15) [m89] ----
    const int r0 = (lane >> 4) * 4;
    #pragma unroll
    for (int ni = 0; ni < 4; ++ni) {
        const int n = n0 + wc * 64 + ni * 16 + cl;
        const float bvv = bias[n];
        #pragma unroll
        for (int mi = 0; mi < 8; ++mi) {
            const int m = m0 + wr * 128 + mi * 16 + r0;
            #pragma unroll
            for (int r = 0; r < 4; ++r)
                C[(size_t)(m + r) * N_TOTAL + n] = acc[mi][ni][r] + bvv;
        }
    }
#undef MFMA_Q
#undef BARRIER
#undef LGKM0
#undef VM
}

// ---------------- fallback: round-1 single kernel (known-good) --------------
__device__ __forceinline__ short f2bf(float f) {
    unsigned u = __builtin_bit_cast(unsigned, f);
    u += 0x7fffu + ((u >> 16) & 1u);
    return (short)(u >> 16);
}

#define FBM 128
#define FBN 128
#define FNWG ((M_TOTAL / FBM) * (N_TOTAL / FBN))   // 1024

__global__ __launch_bounds__(256) void fb_gemm_bias_kernel(
    const float* __restrict__ X, const float* __restrict__ W,
    const float* __restrict__ bias, float* __restrict__ C)
{
    __shared__ short As[FBM * BK];
    __shared__ short Bs[FBN * BK];

    const int tid  = threadIdx.x;
    const int lane = tid & 63;
    const int wave = tid >> 6;
    const int wr = wave >> 1;
    const int wc = wave & 1;

    const int bid  = blockIdx.x;
    const int work = (bid & 7) * (FNWG / 8) + (bid >> 3);
    const int bm = work >> 3;
    const int bn = work & 7;
    const int m0 = bm * FBM, n0 = bn * FBN;

    const int srow  = tid >> 4;
    const int scol4 = tid & 15;

    f32x4 acc[4][4] = {};
    char* const Ab = (char*)As;
    char* const Bb = (char*)Bs;

    for (int k0 = 0; k0 < K_TOTAL; k0 += BK) {
        __syncthreads();
        #pragma unroll
        for (int pass = 0; pass < 8; ++pass) {
            const int row = srow + pass * 16;
            const int off = (row * (BK * 2) + scol4 * 8) ^ ((row & 7) << 4);
            {
                const f32x4 v = *(const f32x4*)(X + (size_t)(m0 + row) * K_TOTAL + k0 + scol4 * 4);
                bf16x4 b;
                b[0] = f2bf(v[0]); b[1] = f2bf(v[1]); b[2] = f2bf(v[2]); b[3] = f2bf(v[3]);
                *(bf16x4*)(Ab + off) = b;
            }
            {
                const f32x4 v = *(const f32x4*)(W + (size_t)(n0 + row) * K_TOTAL + k0 + scol4 * 4);
                bf16x4 b;
                b[0] = f2bf(v[0]); b[1] = f2bf(v[1]); b[2] = f2bf(v[2]); b[3] = f2bf(v[3]);
                *(bf16x4*)(Bb + off) = b;
            }
        }
        __syncthreads();

        #pragma unroll
        for (int ks = 0; ks < 2; ++ks) {
            const int kel = ks * 32 + ((lane >> 4) << 3);
            bf16x8 af[4], bfr[4];
            #pragma unroll
            for (int i = 0; i < 4; ++i) {
                const int arow = wr * 64 + i * 16 + (lane & 15);
                af[i]  = *(const bf16x8*)(Ab + ((arow * (BK * 2) + kel * 2) ^ ((arow & 7) << 4)));
                const int brow = wc * 64 + i * 16 + (lane & 15);
                bfr[i] = *(const bf16x8*)(Bb + ((brow * (BK * 2) + kel * 2) ^ ((brow & 7) << 4)));
            }
            #pragma unroll
            for (int mi = 0; mi < 4; ++mi)
                #pragma unroll
                for (int ni = 0; ni < 4; ++ni)
                    acc[mi][ni] = __builtin_amdgcn_mfma_f32_16x16x32_bf16(
                        af[mi], bfr[ni], acc[mi][ni], 0, 0, 0);
        }
    }

    const int cl = lane & 15;
    const int r0 = (lane >> 4) * 4;
    #pragma unroll
    for (int ni = 0; ni < 4; ++ni) {
        const int n = n0 + wc * 64 + ni * 16 + cl;
        const float bvv = bias[n];
        #pragma unroll
        for (int mi = 0; mi < 4; ++mi) {
            const int m = m0 + wr * 64 + mi * 16 + r0;
            #pragma unroll
            for (int r = 0; r < 4; ++r)
                C[(size_t)(m + r) * N_TOTAL + n] = acc[mi][ni][r] + bvv;
        }
    }
}

extern "C" void kernel_launch(void* const* d_in, const int* in_sizes, int n_in,
                              void* d_out, int out_size, void* d_ws, size_t ws_size,
                              hipStream_t stream) {
    // inputs: 0:X 1:Wq 2:bq 3:Wk 4:bk 5:Wv 6:bv
    // softmax rows sum to 1 => out = X @ Wv^T + bv exactly.
    const float* X  = (const float*)d_in[0];
    const float* Wv = (const float*)d_in[5];
    const float* bv = (const float*)d_in[6];
    float* out = (float*)d_out;

    const size_t XB_BYTES = (size_t)M_TOTAL * K_TOTAL * 2;   // 32 MiB
    const size_t WB_BYTES = (size_t)N_TOTAL * K_TOTAL * 2;   // 2 MiB

    if (ws_size >= XB_BYTES + WB_BYTES) {
        unsigned short* Xb = (unsigned short*)d_ws;
        unsigned short* Wb = (unsigned short*)((char*)d_ws + XB_BYTES);
        cvt2_kernel<<<dim3((N8X + N8W) / 256), dim3(256), 0, stream>>>(
            X, Wv, (uint4*)Xb, (uint4*)Wb);
        gemm8p_kernel<<<dim3(NWG), dim3(512), 0, stream>>>(Xb, Wb, bv, out);
    } else {
        fb_gemm_bias_kernel<<<dim3(FNWG), dim3(256), 0, stream>>>(X, Wv, bv, out);
    }
}